// Round 1
// baseline (79.609 us; speedup 1.0000x reference)
//
#include <hip/hip_runtime.h>

// Projector: out[b,k,d] = sum_l softmax_k( cos(p_k, x[b,l]) ) * x[b,l,d]
// B=4096, L=200, D=64, K=8. fp32 in/out. Memory-bound: single pass over x.

#define LQ 200
#define DQ 64
#define KQ 8

#define TR 64    // rows per LDS tile
#define XS 66    // x tile LDS stride in floats (8B-aligned rows, mild conflicts)
#define AS 68    // attn/score LDS stride in floats (16B-aligned rows)

__global__ __launch_bounds__(64) void proto_norm_kernel(const float* __restrict__ proto,
                                                        float* __restrict__ pn) {
    const int lane = threadIdx.x;  // d
    for (int k = 0; k < KQ; ++k) {
        float v = proto[k * DQ + lane];
        float sq = v * v;
        #pragma unroll
        for (int off = 32; off > 0; off >>= 1) sq += __shfl_xor(sq, off, 64);
        pn[k * DQ + lane] = v * __frsqrt_rn(fmaxf(sq, 1e-12f));
    }
}

__global__ __launch_bounds__(256) void projector_kernel(const float* __restrict__ x,
                                                        const float* __restrict__ pn,
                                                        float* __restrict__ out) {
    __shared__ float xt[TR * XS];     // staged x tile
    __shared__ float sA[KQ * AS];     // scores -> attn, [k][row]

    const int b = blockIdx.x;
    const int t = threadIdx.x;
    const int lane = t & 63;
    // wave id as a provably wave-uniform (SGPR) value -> p-hat reads become s_loads
    const int wid = __builtin_amdgcn_readfirstlane((int)(threadIdx.x >> 6));
    const int k0 = 2 * wid, k1 = 2 * wid + 1;

    // accumulation mapping: thread owns (ak, d-pair)
    const int ak = t >> 5;        // 0..7
    const int am = t & 31;        // pair index
    const int ad = 2 * am;        // d0

    float2 acc = make_float2(0.f, 0.f);

    const float* xb  = x + (size_t)b * (LQ * DQ);
    const float* pk0 = pn + k0 * DQ;
    const float* pk1 = pn + k1 * DQ;

    for (int l0 = 0; l0 < LQ; l0 += TR) {
        const int nr = min(TR, LQ - l0);

        // ---- stage: global -> LDS (coalesced float4 loads, b64 LDS writes)
        #pragma unroll
        for (int i = 0; i < 4; ++i) {
            int q = i * 256 + t;               // quad index within tile
            if (q < nr * 16) {
                float4 v = *(const float4*)(xb + l0 * DQ + q * 4);
                int row = q >> 4;
                int d   = (q & 15) * 4;
                float* dst = &xt[row * XS + d];
                *(float2*)(dst)     = make_float2(v.x, v.y);
                *(float2*)(dst + 2) = make_float2(v.z, v.w);
            }
        }
        __syncthreads();

        // ---- dots: lane = row; this wave computes scores for k0,k1 over all rows
        {
            const int row = lane;
            float s0 = 0.f, s1 = 0.f, sq = 0.f;
            const float* xr = &xt[row * XS];
            #pragma unroll
            for (int d = 0; d < DQ; d += 2) {
                float2 xv = *(const float2*)(xr + d);     // ds_read_b64
                float2 pa = *(const float2*)(pk0 + d);    // scalar (uniform)
                float2 pb = *(const float2*)(pk1 + d);    // scalar (uniform)
                sq += xv.x * xv.x + xv.y * xv.y;
                s0 += xv.x * pa.x + xv.y * pa.y;
                s1 += xv.x * pb.x + xv.y * pb.y;
            }
            float rn = __frsqrt_rn(fmaxf(sq, 1e-12f));
            // rows >= nr compute garbage from stale LDS; never consumed (accum guards)
            sA[k0 * AS + row] = s0 * rn;
            sA[k1 * AS + row] = s1 * rn;
        }
        __syncthreads();

        // ---- softmax over K per row: 4 lanes per row, 2 values each
        // cos in [-1,1] -> exp bounded, no max-subtract needed
        {
            const int row = t >> 2;
            const int kq  = t & 3;
            float e0 = __expf(sA[(2 * kq)     * AS + row]);
            float e1 = __expf(sA[(2 * kq + 1) * AS + row]);
            float ssum = e0 + e1;
            ssum += __shfl_xor(ssum, 1, 64);
            ssum += __shfl_xor(ssum, 2, 64);
            float r = __frcp_rn(ssum);
            sA[(2 * kq)     * AS + row] = e0 * r;
            sA[(2 * kq + 1) * AS + row] = e1 * r;
        }
        __syncthreads();

        // ---- accumulate: acc[k][d-pair] += attn[k][row] * x[row][d-pair]
        {
            const float* ar = &sA[ak * AS];
            int row = 0;
            for (; row + 4 <= nr; row += 4) {
                float4 av = *(const float4*)(ar + row);                 // uniform b128
                float2 x0 = *(const float2*)(&xt[(row + 0) * XS + ad]);
                float2 x1 = *(const float2*)(&xt[(row + 1) * XS + ad]);
                float2 x2 = *(const float2*)(&xt[(row + 2) * XS + ad]);
                float2 x3 = *(const float2*)(&xt[(row + 3) * XS + ad]);
                acc.x += av.x * x0.x + av.y * x1.x + av.z * x2.x + av.w * x3.x;
                acc.y += av.x * x0.y + av.y * x1.y + av.z * x2.y + av.w * x3.y;
            }
            for (; row < nr; ++row) {
                float a = ar[row];
                float2 xv = *(const float2*)(&xt[row * XS + ad]);
                acc.x += a * xv.x;
                acc.y += a * xv.y;
            }
        }
        __syncthreads();
    }

    // ---- epilogue: out[b][ak][ad..ad+1], coalesced float2 stores
    float* op = out + (size_t)b * (KQ * DQ) + ak * DQ + ad;
    *(float2*)op = acc;
}

extern "C" void kernel_launch(void* const* d_in, const int* in_sizes, int n_in,
                              void* d_out, int out_size, void* d_ws, size_t ws_size,
                              hipStream_t stream) {
    const float* x     = (const float*)d_in[0];   // [B, L, D] fp32
    const float* proto = (const float*)d_in[1];   // [K, D] fp32
    float* out = (float*)d_out;                   // [B, K, D] fp32
    float* pn  = (float*)d_ws;                    // normalized prototype (2 KB)

    const int Bn = in_sizes[0] / (LQ * DQ);       // 4096

    proto_norm_kernel<<<1, 64, 0, stream>>>(proto, pn);
    projector_kernel<<<Bn, 256, 0, stream>>>(x, pn, out);
}